// Round 1
// baseline (808.287 us; speedup 1.0000x reference)
//
#include <hip/hip_runtime.h>

// PAU (Padé Activation Unit), version A:
//   z = x + center
//   P(z) = a0 + a1 z + ... + a5 z^5          (Horner)
//   Q(z) = 1 + |z|*(|b1| + |z|*(|b2| + |z|*(|b3| + |z|*|b4|)))
//   out = P / Q
// Elementwise, memory-bound: 1.07 GB traffic -> ~170 us floor at 6.3 TB/s.

__global__ __launch_bounds__(256) void PAU_kernel(
    const float* __restrict__ x,
    const float* __restrict__ center,
    const float* __restrict__ num,   // 6 coeffs a0..a5
    const float* __restrict__ den,   // 4 coeffs b1..b4
    float* __restrict__ out,
    long long n4,                    // number of float4 vectors
    long long n)                     // total elements
{
    // Uniform scalar loads (same address across wave -> s_load, cached).
    const float c  = center[0];
    const float a0 = num[0], a1 = num[1], a2 = num[2],
                a3 = num[3], a4 = num[4], a5 = num[5];
    const float b1 = fabsf(den[0]), b2 = fabsf(den[1]),
                b3 = fabsf(den[2]), b4 = fabsf(den[3]);

    const long long i = (long long)blockIdx.x * blockDim.x + threadIdx.x;

    if (i < n4) {
        float4 v = reinterpret_cast<const float4*>(x)[i];
        float4 r;
        float* vp = &v.x;
        float* rp = &r.x;
#pragma unroll
        for (int k = 0; k < 4; ++k) {
            const float z = vp[k] + c;
            // numerator Horner
            float p = fmaf(a5, z, a4);
            p = fmaf(p, z, a3);
            p = fmaf(p, z, a2);
            p = fmaf(p, z, a1);
            p = fmaf(p, z, a0);
            // denominator Horner on |z|
            const float az = fabsf(z);
            float q = fmaf(b4, az, b3);
            q = fmaf(q, az, b2);
            q = fmaf(q, az, b1);
            q = fmaf(q, az, 1.0f);
            rp[k] = p / q;
        }
        reinterpret_cast<float4*>(out)[i] = r;
    }

    // Scalar tail (n not divisible by 4). Thread 0 of block 0 handles it;
    // for this problem n % 4 == 0 so this is dead code, kept for safety.
    if (i == 0) {
        for (long long t = n4 * 4; t < n; ++t) {
            const float z = x[t] + c;
            float p = fmaf(a5, z, a4);
            p = fmaf(p, z, a3);
            p = fmaf(p, z, a2);
            p = fmaf(p, z, a1);
            p = fmaf(p, z, a0);
            const float az = fabsf(z);
            float q = fmaf(b4, az, b3);
            q = fmaf(q, az, b2);
            q = fmaf(q, az, b1);
            q = fmaf(q, az, 1.0f);
            out[t] = p / q;
        }
    }
}

extern "C" void kernel_launch(void* const* d_in, const int* in_sizes, int n_in,
                              void* d_out, int out_size, void* d_ws, size_t ws_size,
                              hipStream_t stream) {
    const float* x      = (const float*)d_in[0];
    const float* center = (const float*)d_in[1];
    const float* num    = (const float*)d_in[2];
    const float* den    = (const float*)d_in[3];
    float* out          = (float*)d_out;

    const long long n  = (long long)in_sizes[0];
    const long long n4 = n / 4;

    const int block = 256;
    const long long grid = (n4 + block - 1) / block;

    PAU_kernel<<<(unsigned)grid, block, 0, stream>>>(x, center, num, den, out, n4, n);
}